// Round 1
// baseline (1716.434 us; speedup 1.0000x reference)
//
#include <hip/hip_runtime.h>
#include <cstdint>
#include <cstddef>
#include <math.h>

#define C_     512
#define N1_    8192
#define N2_    131072
#define NTOT   139265
#define E_     1000000
#define K1_    820
#define K2_    3280
#define M_     4101

// d_out offsets (float elements), in reference return order
#define OFF_XPOOL   0ull
#define OFF_A       2099712ull
#define OFF_BATCH   18917913ull
#define OFF_CLUSTER 18922014ull
#define OFF_NNT     19061279ull
#define OFF_NTREE   19065380ull
#define OFF_FIT     19069481ull
#define OFF_NXY     19208746ull
#define OUT_TOTAL   19216948ull

// ---------------- norms of weight vectors (f64) ----------------
__global__ void k_norms(const float* __restrict__ w1, const float* __restrict__ w2,
                        double* __restrict__ norms) {
    __shared__ double s1[256], s2[256];
    int t = threadIdx.x;
    double a = 0.0, b = 0.0;
    for (int i = t; i < C_; i += 256) {
        double v1 = (double)w1[i]; a += v1 * v1;
        double v2 = (double)w2[i]; b += v2 * v2;
    }
    s1[t] = a; s2[t] = b;
    __syncthreads();
    for (int off = 128; off > 0; off >>= 1) {
        if (t < off) { s1[t] += s1[t + off]; s2[t] += s2[t + off]; }
        __syncthreads();
    }
    if (t == 0) { norms[0] = sqrt(s1[0]); norms[1] = sqrt(s2[0]); }
}

// ---------------- fitness f = tanh(dot(x,w)/norm), one wave per row ----------------
__global__ void k_fit(const float* __restrict__ x, const float* __restrict__ w,
                      const double* __restrict__ norms, int normIdx,
                      int rowOff, int nRows, double* __restrict__ fd,
                      float* __restrict__ fitOut) {
    int gw = (int)((blockIdx.x * blockDim.x + threadIdx.x) >> 6);
    int lane = threadIdx.x & 63;
    if (gw >= nRows) return;
    const float* row = x + (size_t)(rowOff + gw) * C_;
    double s = 0.0;
    for (int c = lane; c < C_; c += 64) s += (double)row[c] * (double)w[c];
    for (int off = 32; off > 0; off >>= 1) s += __shfl_down(s, off, 64);
    if (lane == 0) {
        double f = tanh(s / norms[normIdx]);
        fd[gw] = f;
        fitOut[gw] = (float)f;
    }
}

// ---------------- rank of f1 (stable), emit decile thresholds ----------------
__global__ void k_rank(const double* __restrict__ f1d, int* __restrict__ thr1) {
    __shared__ double buf[2048];
    int i = blockIdx.x * 256 + threadIdx.x;
    double fi = f1d[i];
    int rank = 0;
    for (int base = 0; base < N1_; base += 2048) {
        __syncthreads();
        for (int j = threadIdx.x; j < 2048; j += 256) buf[j] = f1d[base + j];
        __syncthreads();
        for (int j = 0; j < 2048; ++j) {
            double fj = buf[j];
            int jj = base + j;
            rank += (int)((fj < fi) || (fj == fi && jj < i));
        }
    }
    if (rank % 10 == 0) thr1[rank / 10] = i;
}

__global__ void k_thr_gather(const int* __restrict__ thr1, const float* __restrict__ xy,
                             const double* __restrict__ f1d, double* __restrict__ thrXYF) {
    int k = blockIdx.x * blockDim.x + threadIdx.x;
    if (k >= K1_) return;
    int i = thr1[k];
    thrXYF[3 * k + 0] = (double)xy[(size_t)(1 + i) * 2 + 0];
    thrXYF[3 * k + 1] = (double)xy[(size_t)(1 + i) * 2 + 1];
    thrXYF[3 * k + 2] = f1d[i];
}

// ---------------- level-1 clustering: argmin over K1 thresholds ----------------
__global__ void k_cluster1(const float* __restrict__ xy, const double* __restrict__ f1d,
                           const double* __restrict__ thrXYF,
                           int* __restrict__ cluster1, int* __restrict__ clusterAll,
                           float* __restrict__ outCluster) {
    __shared__ double t[K1_ * 3];
    for (int j = threadIdx.x; j < K1_ * 3; j += blockDim.x) t[j] = thrXYF[j];
    __syncthreads();
    int i = blockIdx.x * blockDim.x + threadIdx.x;
    if (blockIdx.x == 0 && threadIdx.x == 0) { clusterAll[0] = 0; }
    if (i >= N1_) return;
    double xi = (double)xy[(size_t)(1 + i) * 2 + 0];
    double yi = (double)xy[(size_t)(1 + i) * 2 + 1];
    double fi = f1d[i];
    double best = INFINITY; int bk = 0;
    for (int k = 0; k < K1_; ++k) {
        double dx = t[3 * k + 0] - xi;
        double dy = t[3 * k + 1] - yi;
        double df = t[3 * k + 2] - fi;
        double d = sqrt(dx * dx + dy * dy) + fabs(df);
        if (d < best) { best = d; bk = k; }
    }
    cluster1[i] = bk;
    clusterAll[1 + i] = bk + 1;
    outCluster[1 + i] = (float)(bk + 1);
}

// ---------------- min(tree2) ----------------
__global__ void k_mintree(const int* __restrict__ tree, int* __restrict__ minTree) {
    int i = blockIdx.x * blockDim.x + threadIdx.x;
    if (i >= N2_) return;
    int v = tree[1 + N1_ + i];
    for (int off = 32; off > 0; off >>= 1) v = min(v, __shfl_down(v, off, 64));
    if ((threadIdx.x & 63) == 0) atomicMin(minTree, v);
}

// ---------------- parents + per-parent counts ----------------
__global__ void k_parents(const int* __restrict__ tree, const int* __restrict__ cluster1,
                          const int* __restrict__ minTree,
                          int* __restrict__ parents, int* __restrict__ countP) {
    int i = blockIdx.x * blockDim.x + threadIdx.x;
    if (i >= N2_) return;
    int p = cluster1[tree[1 + N1_ + i] - minTree[0]];
    parents[i] = p;
    atomicAdd(&countP[p], 1);
}

// ---------------- single-block exclusive scan (n up to ~5k) ----------------
__global__ void k_scan(const int* __restrict__ cnt, int* __restrict__ start, int n) {
    __shared__ int partial[1024];
    int t = threadIdx.x;
    int per = (n + 1023) / 1024;
    int lo = t * per;
    int hi = lo + per; if (hi > n) hi = n;
    int s = 0;
    if (lo < n) for (int i = lo; i < hi; ++i) s += cnt[i];
    partial[t] = s;
    __syncthreads();
    for (int off = 1; off < 1024; off <<= 1) {
        int v = (t >= off) ? partial[t - off] : 0;
        __syncthreads();
        partial[t] += v;
        __syncthreads();
    }
    int base = (t > 0) ? partial[t - 1] : 0;
    if (lo < n) for (int i = lo; i < hi; ++i) { start[i] = base; base += cnt[i]; }
    if (t == 1023) start[n] = partial[1023];
}

__global__ void k_scatterP(const int* __restrict__ parents, const int* __restrict__ startP,
                           int* __restrict__ fillP, int* __restrict__ plist) {
    int i = blockIdx.x * blockDim.x + threadIdx.x;
    if (i >= N2_) return;
    int p = parents[i];
    int pos = startP[p] + atomicAdd(&fillP[p], 1);
    plist[pos] = i;
}

// ---------------- per-parent first-4 in (comp_key, index) order ----------------
__global__ void k_top4(const int* __restrict__ startP, const int* __restrict__ plist,
                       const double* __restrict__ f2d, int* __restrict__ cand) {
    int p = blockIdx.x * blockDim.x + threadIdx.x;
    if (p >= K1_) return;
    int lo = startP[p], hi = startP[p + 1];
    double bk[4] = {1e300, 1e300, 1e300, 1e300};
    int bi[4] = {-1, -1, -1, -1};
    for (int q = lo; q < hi; ++q) {
        int idx = plist[q];
        double key = 4.0 * (double)p + f2d[idx];
        for (int j = 0; j < 4; ++j) {
            bool less = (key < bk[j]) || (key == bk[j] && (unsigned)idx < (unsigned)bi[j]);
            if (less) {
                for (int r = 3; r > j; --r) { bk[r] = bk[r - 1]; bi[r] = bi[r - 1]; }
                bk[j] = key; bi[j] = idx;
                break;
            }
        }
    }
    for (int j = 0; j < 4; ++j) cand[4 * p + j] = bi[j];
}

// ---------------- level-2 clustering: argmin over parent's 4 candidates ----------------
__global__ void k_cluster2(const float* __restrict__ xy, const double* __restrict__ f2d,
                           const int* __restrict__ parents, const int* __restrict__ cand,
                           int* __restrict__ clusterAll, float* __restrict__ outCluster) {
    int i = blockIdx.x * blockDim.x + threadIdx.x;
    if (i >= N2_) return;
    int p = parents[i];
    double xi = (double)xy[(size_t)(1 + N1_ + i) * 2 + 0];
    double yi = (double)xy[(size_t)(1 + N1_ + i) * 2 + 1];
    double fi = f2d[i];
    double best = INFINITY; int bj = 0;
    for (int j = 0; j < 4; ++j) {
        int cidx = cand[4 * p + j];
        double d;
        if (cidx < 0) {
            d = INFINITY;
        } else {
            double dx = (double)xy[(size_t)(1 + N1_ + cidx) * 2 + 0] - xi;
            double dy = (double)xy[(size_t)(1 + N1_ + cidx) * 2 + 1] - yi;
            double df = f2d[cidx] - fi;
            d = sqrt(dx * dx + dy * dy) + fabs(df);
        }
        if (d < best) { best = d; bj = j; }
    }
    int c2 = p * 4 + bj;
    clusterAll[1 + N1_ + i] = c2 + 1 + K1_;
    outCluster[1 + N1_ + i] = (float)(c2 + 1 + K1_);
}

// ---------------- bucket all N nodes by final cluster ----------------
__global__ void k_countM(const int* __restrict__ clusterAll, int* __restrict__ cntM) {
    int i = blockIdx.x * blockDim.x + threadIdx.x;
    if (i >= NTOT) return;
    atomicAdd(&cntM[clusterAll[i]], 1);
}

__global__ void k_scatterM(const int* __restrict__ clusterAll, const int* __restrict__ startM,
                           int* __restrict__ fillM, int* __restrict__ clusterList) {
    int i = blockIdx.x * blockDim.x + threadIdx.x;
    if (i >= NTOT) return;
    int c = clusterAll[i];
    int pos = startM[c] + atomicAdd(&fillM[c], 1);
    clusterList[pos] = i;
}

// ---------------- pooled features + pooled xy: one block per cluster ----------------
__global__ void k_pool(const float* __restrict__ x, const float* __restrict__ xy,
                       const int* __restrict__ startM, const int* __restrict__ clusterList,
                       float* __restrict__ out) {
    int m = blockIdx.x;
    int lo = startM[m], hi = startM[m + 1];
    int t = threadIdx.x;
    double s0 = 0.0, s1 = 0.0, sx = 0.0, sy = 0.0;
    for (int q = lo; q < hi; ++q) {
        int node = clusterList[q];
        const float* row = x + (size_t)node * C_;
        s0 += (double)row[t];
        s1 += (double)row[t + 256];
        if (t == 0) sx += (double)xy[(size_t)node * 2 + 0];
        if (t == 1) sy += (double)xy[(size_t)node * 2 + 1];
    }
    double cnt = (double)((hi - lo) > 0 ? (hi - lo) : 1);
    float* xp = out + OFF_XPOOL;
    xp[(size_t)m * C_ + t] = (float)(s0 / cnt);
    xp[(size_t)m * C_ + t + 256] = (float)(s1 / cnt);
    if (t == 0) out[OFF_NXY + 2 * (size_t)m + 0] = (float)(sx / cnt);
    if (t == 1) out[OFF_NXY + 2 * (size_t)m + 1] = (float)(sy / cnt);
}

// ---------------- adjacency ----------------
__global__ void k_edges(const int* __restrict__ ei, const int* __restrict__ clusterAll,
                        float* __restrict__ A) {
    int e = blockIdx.x * blockDim.x + threadIdx.x;
    if (e >= E_) return;
    int r = clusterAll[ei[e]];
    int c = clusterAll[ei[E_ + e]];
    atomicAdd(&A[(size_t)r * M_ + c], 1.0f);
}

__global__ void k_selfloops(const int* __restrict__ clusterAll, float* __restrict__ A) {
    int i = blockIdx.x * blockDim.x + threadIdx.x;
    if (i >= NTOT) return;
    int c = clusterAll[i];
    atomicAdd(&A[(size_t)c * M_ + c], 1.0f);
}

// ---------------- trivial outputs ----------------
__global__ void k_trivial(float* __restrict__ out) {
    int i = blockIdx.x * blockDim.x + threadIdx.x;
    if (i >= M_) return;
    out[OFF_NNT + i] = (i == 0) ? 0.0f : (i <= K1_ ? 1.0f : 2.0f);
    out[OFF_NTREE + i] = (i == 0) ? -1.0f : (i <= K1_ ? 0.0f : (float)(1 + (i - 1 - K1_) / 4));
}

extern "C" void kernel_launch(void* const* d_in, const int* in_sizes, int n_in,
                              void* d_out, int out_size, void* d_ws, size_t ws_size,
                              hipStream_t stream) {
    const float* x    = (const float*)d_in[0];
    const int*   ei   = (const int*)d_in[1];
    const int*   tree = (const int*)d_in[3];
    const float* xy   = (const float*)d_in[4];
    const float* w1   = (const float*)d_in[5];
    const float* w2   = (const float*)d_in[6];
    float* out = (float*)d_out;

    char* p = (char*)d_ws;
    auto alloc = [&](size_t nbytes) -> char* {
        char* r = p;
        p += (nbytes + 255) & ~(size_t)255;
        return r;
    };
    double* f1d        = (double*)alloc((size_t)N1_ * 8);
    double* f2d        = (double*)alloc((size_t)N2_ * 8);
    double* norms      = (double*)alloc(16);
    int*    thr1       = (int*)alloc((size_t)K1_ * 4);
    double* thrXYF     = (double*)alloc((size_t)K1_ * 3 * 8);
    int*    cluster1   = (int*)alloc((size_t)N1_ * 4);
    int*    clusterAll = (int*)alloc((size_t)NTOT * 4);
    int*    parentsA   = (int*)alloc((size_t)N2_ * 4);
    int*    plist      = (int*)alloc((size_t)N2_ * 4);
    int*    clusterLst = (int*)alloc((size_t)NTOT * 4);
    int*    startP     = (int*)alloc((size_t)(K1_ + 1) * 4);
    int*    startM     = (int*)alloc((size_t)(M_ + 1) * 4);
    char*   zeroBlk    = alloc((size_t)(K1_ + K1_ + M_ + M_) * 4);
    int*    countP     = (int*)zeroBlk;
    int*    fillP      = countP + K1_;
    int*    cntM       = fillP + K1_;
    int*    fillM      = cntM + M_;
    int*    cand       = (int*)alloc((size_t)K1_ * 4 * 4);
    int*    minTree    = (int*)alloc(4);

    hipMemsetAsync(d_out, 0, OUT_TOTAL * 4, stream);
    hipMemsetAsync(zeroBlk, 0, (size_t)(K1_ + K1_ + M_ + M_) * 4, stream);
    hipMemsetAsync(cand, 0xFF, (size_t)K1_ * 16, stream);   // -1
    hipMemsetAsync(minTree, 0x7F, 4, stream);               // large positive int

    k_norms<<<1, 256, 0, stream>>>(w1, w2, norms);
    k_fit<<<N1_ / 4, 256, 0, stream>>>(x, w1, norms, 0, 1, N1_, f1d, out + OFF_FIT + 1);
    k_fit<<<N2_ / 4, 256, 0, stream>>>(x, w2, norms, 1, 1 + N1_, N2_, f2d, out + OFF_FIT + 1 + N1_);
    k_rank<<<N1_ / 256, 256, 0, stream>>>(f1d, thr1);
    k_thr_gather<<<(K1_ + 255) / 256, 256, 0, stream>>>(thr1, xy, f1d, thrXYF);
    k_cluster1<<<N1_ / 256, 256, 0, stream>>>(xy, f1d, thrXYF, cluster1, clusterAll,
                                              out + OFF_CLUSTER);
    k_mintree<<<N2_ / 256, 256, 0, stream>>>(tree, minTree);
    k_parents<<<N2_ / 256, 256, 0, stream>>>(tree, cluster1, minTree, parentsA, countP);
    k_scan<<<1, 1024, 0, stream>>>(countP, startP, K1_);
    k_scatterP<<<N2_ / 256, 256, 0, stream>>>(parentsA, startP, fillP, plist);
    k_top4<<<(K1_ + 255) / 256, 256, 0, stream>>>(startP, plist, f2d, cand);
    k_cluster2<<<N2_ / 256, 256, 0, stream>>>(xy, f2d, parentsA, cand, clusterAll,
                                              out + OFF_CLUSTER);
    k_countM<<<(NTOT + 255) / 256, 256, 0, stream>>>(clusterAll, cntM);
    k_scan<<<1, 1024, 0, stream>>>(cntM, startM, M_);
    k_scatterM<<<(NTOT + 255) / 256, 256, 0, stream>>>(clusterAll, startM, fillM, clusterLst);
    k_pool<<<M_, 256, 0, stream>>>(x, xy, startM, clusterLst, out);
    k_edges<<<(E_ + 255) / 256, 256, 0, stream>>>(ei, clusterAll, out + OFF_A);
    k_selfloops<<<(NTOT + 255) / 256, 256, 0, stream>>>(clusterAll, out + OFF_A);
    k_trivial<<<(M_ + 255) / 256, 256, 0, stream>>>(out);
}

// Round 2
// 1040.825 us; speedup vs baseline: 1.6491x; 1.6491x over previous
//
#include <hip/hip_runtime.h>
#include <cstdint>
#include <cstddef>
#include <math.h>

#define C_     512
#define N1_    8192
#define N2_    131072
#define NTOT   139265
#define E_     1000000
#define K1_    820
#define K2_    3280
#define M_     4101

// d_out offsets (float elements), in reference return order
#define OFF_XPOOL   0ull
#define OFF_A       2099712ull
#define OFF_BATCH   18917913ull
#define OFF_CLUSTER 18922014ull
#define OFF_NNT     19061279ull
#define OFF_NTREE   19065380ull
#define OFF_FIT     19069481ull
#define OFF_NXY     19208746ull
#define OUT_TOTAL   19216948ull

// ---------------- norms of weight vectors (f64) ----------------
__global__ void k_norms(const float* __restrict__ w1, const float* __restrict__ w2,
                        double* __restrict__ norms) {
    __shared__ double s1[256], s2[256];
    int t = threadIdx.x;
    double a = 0.0, b = 0.0;
    for (int i = t; i < C_; i += 256) {
        double v1 = (double)w1[i]; a += v1 * v1;
        double v2 = (double)w2[i]; b += v2 * v2;
    }
    s1[t] = a; s2[t] = b;
    __syncthreads();
    for (int off = 128; off > 0; off >>= 1) {
        if (t < off) { s1[t] += s1[t + off]; s2[t] += s2[t + off]; }
        __syncthreads();
    }
    if (t == 0) { norms[0] = sqrt(s1[0]); norms[1] = sqrt(s2[0]); }
}

// ---------------- fitness f = tanh(dot(x,w)/norm), one wave per row ----------------
__global__ void k_fit(const float* __restrict__ x, const float* __restrict__ w,
                      const double* __restrict__ norms, int normIdx,
                      int rowOff, int nRows, double* __restrict__ fd,
                      float* __restrict__ fitOut) {
    int gw = (int)((blockIdx.x * blockDim.x + threadIdx.x) >> 6);
    int lane = threadIdx.x & 63;
    if (gw >= nRows) return;
    const float* row = x + (size_t)(rowOff + gw) * C_;
    double s = 0.0;
    for (int c = lane; c < C_; c += 64) s += (double)row[c] * (double)w[c];
    for (int off = 32; off > 0; off >>= 1) s += __shfl_down(s, off, 64);
    if (lane == 0) {
        double f = tanh(s / norms[normIdx]);
        fd[gw] = f;
        fitOut[gw] = (float)f;
    }
}

// ---------------- rank of f1 (stable), emit decile thresholds ----------------
__global__ void k_rank(const double* __restrict__ f1d, int* __restrict__ thr1) {
    __shared__ double buf[2048];
    int i = blockIdx.x * 256 + threadIdx.x;
    double fi = f1d[i];
    int rank = 0;
    for (int base = 0; base < N1_; base += 2048) {
        __syncthreads();
        for (int j = threadIdx.x; j < 2048; j += 256) buf[j] = f1d[base + j];
        __syncthreads();
        for (int j = 0; j < 2048; ++j) {
            double fj = buf[j];
            int jj = base + j;
            rank += (int)((fj < fi) || (fj == fi && jj < i));
        }
    }
    if (rank % 10 == 0) thr1[rank / 10] = i;
}

__global__ void k_thr_gather(const int* __restrict__ thr1, const float* __restrict__ xy,
                             const double* __restrict__ f1d, double* __restrict__ thrXYF) {
    int k = blockIdx.x * blockDim.x + threadIdx.x;
    if (k >= K1_) return;
    int i = thr1[k];
    thrXYF[3 * k + 0] = (double)xy[(size_t)(1 + i) * 2 + 0];
    thrXYF[3 * k + 1] = (double)xy[(size_t)(1 + i) * 2 + 1];
    thrXYF[3 * k + 2] = f1d[i];
}

// ---------------- level-1 clustering: one wave per row, lanes split K1 ----------------
__global__ void k_cluster1(const float* __restrict__ xy, const double* __restrict__ f1d,
                           const double* __restrict__ thrXYF,
                           int* __restrict__ cluster1, int* __restrict__ clusterAll,
                           float* __restrict__ outCluster) {
    __shared__ double t[K1_ * 3];
    for (int j = threadIdx.x; j < K1_ * 3; j += blockDim.x) t[j] = thrXYF[j];
    __syncthreads();
    if (blockIdx.x == 0 && threadIdx.x == 0) { clusterAll[0] = 0; }
    int gw = blockIdx.x * (blockDim.x >> 6) + (threadIdx.x >> 6);
    int lane = threadIdx.x & 63;
    if (gw >= N1_) return;
    double xi = (double)xy[(size_t)(1 + gw) * 2 + 0];
    double yi = (double)xy[(size_t)(1 + gw) * 2 + 1];
    double fi = f1d[gw];
    double best = INFINITY; int bk = 0x7fffffff;
    for (int k = lane; k < K1_; k += 64) {
        double dx = t[3 * k + 0] - xi;
        double dy = t[3 * k + 1] - yi;
        double df = t[3 * k + 2] - fi;
        double d = sqrt(dx * dx + dy * dy) + fabs(df);
        if (d < best || (d == best && k < bk)) { best = d; bk = k; }
    }
    for (int off = 32; off > 0; off >>= 1) {
        double ob = __shfl_down(best, off, 64);
        int ok = __shfl_down(bk, off, 64);
        if (ob < best || (ob == best && ok < bk)) { best = ob; bk = ok; }
    }
    if (lane == 0) {
        cluster1[gw] = bk;
        clusterAll[1 + gw] = bk + 1;
        outCluster[1 + gw] = (float)(bk + 1);
    }
}

// ---------------- min(tree2) ----------------
__global__ void k_mintree(const int* __restrict__ tree, int* __restrict__ minTree) {
    int i = blockIdx.x * blockDim.x + threadIdx.x;
    if (i >= N2_) return;
    int v = tree[1 + N1_ + i];
    for (int off = 32; off > 0; off >>= 1) v = min(v, __shfl_down(v, off, 64));
    if ((threadIdx.x & 63) == 0) atomicMin(minTree, v);
}

// ---------------- parents + per-parent counts ----------------
__global__ void k_parents(const int* __restrict__ tree, const int* __restrict__ cluster1,
                          const int* __restrict__ minTree,
                          int* __restrict__ parents, int* __restrict__ countP) {
    int i = blockIdx.x * blockDim.x + threadIdx.x;
    if (i >= N2_) return;
    int p = cluster1[tree[1 + N1_ + i] - minTree[0]];
    parents[i] = p;
    atomicAdd(&countP[p], 1);
}

// ---------------- single-block exclusive scan (n up to ~5k) ----------------
__global__ void k_scan(const int* __restrict__ cnt, int* __restrict__ start, int n) {
    __shared__ int partial[1024];
    int t = threadIdx.x;
    int per = (n + 1023) / 1024;
    int lo = t * per;
    int hi = lo + per; if (hi > n) hi = n;
    int s = 0;
    if (lo < n) for (int i = lo; i < hi; ++i) s += cnt[i];
    partial[t] = s;
    __syncthreads();
    for (int off = 1; off < 1024; off <<= 1) {
        int v = (t >= off) ? partial[t - off] : 0;
        __syncthreads();
        partial[t] += v;
        __syncthreads();
    }
    int base = (t > 0) ? partial[t - 1] : 0;
    if (lo < n) for (int i = lo; i < hi; ++i) { start[i] = base; base += cnt[i]; }
    if (t == 1023) start[n] = partial[1023];
}

__global__ void k_scatterP(const int* __restrict__ parents, const int* __restrict__ startP,
                           int* __restrict__ fillP, int* __restrict__ plist) {
    int i = blockIdx.x * blockDim.x + threadIdx.x;
    if (i >= N2_) return;
    int p = parents[i];
    int pos = startP[p] + atomicAdd(&fillP[p], 1);
    plist[pos] = i;
}

// ---------------- per-parent first-4 in (f2, index) order: one wave per parent ----------------
__global__ void k_top4(const int* __restrict__ startP, const int* __restrict__ plist,
                       const double* __restrict__ f2d, int* __restrict__ cand) {
    int p = blockIdx.x * (blockDim.x >> 6) + (threadIdx.x >> 6);
    int lane = threadIdx.x & 63;
    if (p >= K1_) return;
    int lo = startP[p], hi = startP[p + 1];
    double bk[4] = {INFINITY, INFINITY, INFINITY, INFINITY};
    int bi[4] = {-1, -1, -1, -1};
    for (int q = lo + lane; q < hi; q += 64) {
        int idx = plist[q];
        double key = f2d[idx];
        for (int j = 0; j < 4; ++j) {
            bool less = (key < bk[j]) || (key == bk[j] && (unsigned)idx < (unsigned)bi[j]);
            if (less) {
                for (int r = 3; r > j; --r) { bk[r] = bk[r - 1]; bi[r] = bi[r - 1]; }
                bk[j] = key; bi[j] = idx;
                break;
            }
        }
    }
    // butterfly merge of sorted 4-lists across the wave
    for (int off = 1; off < 64; off <<= 1) {
        double ok_[4]; int oi[4];
        for (int j = 0; j < 4; ++j) {
            ok_[j] = __shfl_xor(bk[j], off, 64);
            oi[j]  = __shfl_xor(bi[j], off, 64);
        }
        double nk[4]; int ni[4];
        int ia = 0, ib = 0;
        for (int j = 0; j < 4; ++j) {
            bool takeA = (bk[ia] < ok_[ib]) ||
                         (bk[ia] == ok_[ib] && (unsigned)bi[ia] <= (unsigned)oi[ib]);
            if (takeA) { nk[j] = bk[ia]; ni[j] = bi[ia]; ++ia; }
            else       { nk[j] = ok_[ib]; ni[j] = oi[ib]; ++ib; }
        }
        for (int j = 0; j < 4; ++j) { bk[j] = nk[j]; bi[j] = ni[j]; }
    }
    if (lane == 0) {
        for (int j = 0; j < 4; ++j) cand[4 * p + j] = bi[j];
    }
}

// ---------------- level-2 clustering: argmin over parent's 4 candidates ----------------
__global__ void k_cluster2(const float* __restrict__ xy, const double* __restrict__ f2d,
                           const int* __restrict__ parents, const int* __restrict__ cand,
                           int* __restrict__ clusterAll, float* __restrict__ outCluster) {
    int i = blockIdx.x * blockDim.x + threadIdx.x;
    if (i >= N2_) return;
    int p = parents[i];
    double xi = (double)xy[(size_t)(1 + N1_ + i) * 2 + 0];
    double yi = (double)xy[(size_t)(1 + N1_ + i) * 2 + 1];
    double fi = f2d[i];
    double best = INFINITY; int bj = 0;
    for (int j = 0; j < 4; ++j) {
        int cidx = cand[4 * p + j];
        double d;
        if (cidx < 0) {
            d = INFINITY;
        } else {
            double dx = (double)xy[(size_t)(1 + N1_ + cidx) * 2 + 0] - xi;
            double dy = (double)xy[(size_t)(1 + N1_ + cidx) * 2 + 1] - yi;
            double df = f2d[cidx] - fi;
            d = sqrt(dx * dx + dy * dy) + fabs(df);
        }
        if (d < best) { best = d; bj = j; }
    }
    int c2 = p * 4 + bj;
    clusterAll[1 + N1_ + i] = c2 + 1 + K1_;
    outCluster[1 + N1_ + i] = (float)(c2 + 1 + K1_);
}

// ---------------- bucket all N nodes by final cluster ----------------
__global__ void k_countM(const int* __restrict__ clusterAll, int* __restrict__ cntM) {
    int i = blockIdx.x * blockDim.x + threadIdx.x;
    if (i >= NTOT) return;
    atomicAdd(&cntM[clusterAll[i]], 1);
}

__global__ void k_scatterM(const int* __restrict__ clusterAll, const int* __restrict__ startM,
                           int* __restrict__ fillM, int* __restrict__ clusterList) {
    int i = blockIdx.x * blockDim.x + threadIdx.x;
    if (i >= NTOT) return;
    int c = clusterAll[i];
    int pos = startM[c] + atomicAdd(&fillM[c], 1);
    clusterList[pos] = i;
}

// ---------------- pooled features + pooled xy: one block per cluster ----------------
__global__ void k_pool(const float* __restrict__ x, const float* __restrict__ xy,
                       const int* __restrict__ startM, const int* __restrict__ clusterList,
                       float* __restrict__ out) {
    int m = blockIdx.x;
    int lo = startM[m], hi = startM[m + 1];
    int t = threadIdx.x;
    double s0 = 0.0, s1 = 0.0, sx = 0.0, sy = 0.0;
    for (int q = lo; q < hi; ++q) {
        int node = clusterList[q];
        const float* row = x + (size_t)node * C_;
        s0 += (double)row[t];
        s1 += (double)row[t + 256];
        if (t == 0) sx += (double)xy[(size_t)node * 2 + 0];
        if (t == 1) sy += (double)xy[(size_t)node * 2 + 1];
    }
    double cnt = (double)((hi - lo) > 0 ? (hi - lo) : 1);
    float* xp = out + OFF_XPOOL;
    xp[(size_t)m * C_ + t] = (float)(s0 / cnt);
    xp[(size_t)m * C_ + t + 256] = (float)(s1 / cnt);
    if (t == 0) out[OFF_NXY + 2 * (size_t)m + 0] = (float)(sx / cnt);
    if (t == 1) out[OFF_NXY + 2 * (size_t)m + 1] = (float)(sy / cnt);
}

// ---------------- adjacency ----------------
__global__ void k_edges(const int* __restrict__ ei, const int* __restrict__ clusterAll,
                        float* __restrict__ A) {
    int e = blockIdx.x * blockDim.x + threadIdx.x;
    if (e >= E_) return;
    int r = clusterAll[ei[e]];
    int c = clusterAll[ei[E_ + e]];
    atomicAdd(&A[(size_t)r * M_ + c], 1.0f);
}

__global__ void k_selfloops(const int* __restrict__ clusterAll, float* __restrict__ A) {
    int i = blockIdx.x * blockDim.x + threadIdx.x;
    if (i >= NTOT) return;
    int c = clusterAll[i];
    atomicAdd(&A[(size_t)c * M_ + c], 1.0f);
}

// ---------------- trivial outputs ----------------
__global__ void k_trivial(float* __restrict__ out) {
    int i = blockIdx.x * blockDim.x + threadIdx.x;
    if (i >= M_) return;
    out[OFF_NNT + i] = (i == 0) ? 0.0f : (i <= K1_ ? 1.0f : 2.0f);
    out[OFF_NTREE + i] = (i == 0) ? -1.0f : (i <= K1_ ? 0.0f : (float)(1 + (i - 1 - K1_) / 4));
}

extern "C" void kernel_launch(void* const* d_in, const int* in_sizes, int n_in,
                              void* d_out, int out_size, void* d_ws, size_t ws_size,
                              hipStream_t stream) {
    const float* x    = (const float*)d_in[0];
    const int*   ei   = (const int*)d_in[1];
    const int*   tree = (const int*)d_in[3];
    const float* xy   = (const float*)d_in[4];
    const float* w1   = (const float*)d_in[5];
    const float* w2   = (const float*)d_in[6];
    float* out = (float*)d_out;

    char* p = (char*)d_ws;
    auto alloc = [&](size_t nbytes) -> char* {
        char* r = p;
        p += (nbytes + 255) & ~(size_t)255;
        return r;
    };
    double* f1d        = (double*)alloc((size_t)N1_ * 8);
    double* f2d        = (double*)alloc((size_t)N2_ * 8);
    double* norms      = (double*)alloc(16);
    int*    thr1       = (int*)alloc((size_t)K1_ * 4);
    double* thrXYF     = (double*)alloc((size_t)K1_ * 3 * 8);
    int*    cluster1   = (int*)alloc((size_t)N1_ * 4);
    int*    clusterAll = (int*)alloc((size_t)NTOT * 4);
    int*    parentsA   = (int*)alloc((size_t)N2_ * 4);
    int*    plist      = (int*)alloc((size_t)N2_ * 4);
    int*    clusterLst = (int*)alloc((size_t)NTOT * 4);
    int*    startP     = (int*)alloc((size_t)(K1_ + 1) * 4);
    int*    startM     = (int*)alloc((size_t)(M_ + 1) * 4);
    char*   zeroBlk    = alloc((size_t)(K1_ + K1_ + M_ + M_) * 4);
    int*    countP     = (int*)zeroBlk;
    int*    fillP      = countP + K1_;
    int*    cntM       = fillP + K1_;
    int*    fillM      = cntM + M_;
    int*    cand       = (int*)alloc((size_t)K1_ * 4 * 4);
    int*    minTree    = (int*)alloc(4);

    hipMemsetAsync(d_out, 0, OUT_TOTAL * 4, stream);
    hipMemsetAsync(zeroBlk, 0, (size_t)(K1_ + K1_ + M_ + M_) * 4, stream);
    hipMemsetAsync(cand, 0xFF, (size_t)K1_ * 16, stream);   // -1
    hipMemsetAsync(minTree, 0x7F, 4, stream);               // large positive int

    k_norms<<<1, 256, 0, stream>>>(w1, w2, norms);
    k_fit<<<N1_ / 4, 256, 0, stream>>>(x, w1, norms, 0, 1, N1_, f1d, out + OFF_FIT + 1);
    k_fit<<<N2_ / 4, 256, 0, stream>>>(x, w2, norms, 1, 1 + N1_, N2_, f2d, out + OFF_FIT + 1 + N1_);
    k_rank<<<N1_ / 256, 256, 0, stream>>>(f1d, thr1);
    k_thr_gather<<<(K1_ + 255) / 256, 256, 0, stream>>>(thr1, xy, f1d, thrXYF);
    k_cluster1<<<N1_ / 4, 256, 0, stream>>>(xy, f1d, thrXYF, cluster1, clusterAll,
                                            out + OFF_CLUSTER);
    k_mintree<<<N2_ / 256, 256, 0, stream>>>(tree, minTree);
    k_parents<<<N2_ / 256, 256, 0, stream>>>(tree, cluster1, minTree, parentsA, countP);
    k_scan<<<1, 1024, 0, stream>>>(countP, startP, K1_);
    k_scatterP<<<N2_ / 256, 256, 0, stream>>>(parentsA, startP, fillP, plist);
    k_top4<<<(K1_ + 3) / 4, 256, 0, stream>>>(startP, plist, f2d, cand);
    k_cluster2<<<N2_ / 256, 256, 0, stream>>>(xy, f2d, parentsA, cand, clusterAll,
                                              out + OFF_CLUSTER);
    k_countM<<<(NTOT + 255) / 256, 256, 0, stream>>>(clusterAll, cntM);
    k_scan<<<1, 1024, 0, stream>>>(cntM, startM, M_);
    k_scatterM<<<(NTOT + 255) / 256, 256, 0, stream>>>(clusterAll, startM, fillM, clusterLst);
    k_pool<<<M_, 256, 0, stream>>>(x, xy, startM, clusterLst, out);
    k_edges<<<(E_ + 255) / 256, 256, 0, stream>>>(ei, clusterAll, out + OFF_A);
    k_selfloops<<<(NTOT + 255) / 256, 256, 0, stream>>>(clusterAll, out + OFF_A);
    k_trivial<<<(M_ + 255) / 256, 256, 0, stream>>>(out);
}

// Round 6
// 835.282 us; speedup vs baseline: 2.0549x; 1.2461x over previous
//
#include <hip/hip_runtime.h>
#include <cstdint>
#include <cstddef>
#include <math.h>

#define C_     512
#define N1_    8192
#define N2_    131072
#define NTOT   139265
#define E_     1000000
#define K1_    820
#define K2_    3280
#define M_     4101
#define NB2    256      // N2 / 512
#define NBM    273      // ceil(NTOT / 512)

// d_out offsets (float elements), in reference return order
#define OFF_XPOOL   0ull
#define OFF_A       2099712ull
#define OFF_BATCH   18917913ull
#define OFF_CLUSTER 18922014ull
#define OFF_NNT     19061279ull
#define OFF_NTREE   19065380ull
#define OFF_FIT     19069481ull
#define OFF_NXY     19208746ull
#define OUT_TOTAL   19216948ull

// Discrete decisions emulate the reference's float32 arithmetic bit-exactly:
// numpy pairwise summation for the dot products / norm, __f*_rn elementwise
// ops (no fma contraction), f32 keys, stable index tiebreaks.
// Bucket lists (plist/clusterLst) are built with a STABLE deterministic
// scatter so every call produces bit-identical output regardless of
// scheduling (round-5 post-timing divergence).

// ---------------- zero a float region with float4 stores ----------------
__global__ void k_zero4(float4* __restrict__ p, long n4, float* __restrict__ tail, int ntail) {
    long i = (long)blockIdx.x * blockDim.x + threadIdx.x;
    long stride = (long)gridDim.x * blockDim.x;
    float4 z = make_float4(0.f, 0.f, 0.f, 0.f);
    for (; i < n4; i += stride) p[i] = z;
    if (blockIdx.x == 0 && threadIdx.x < ntail) tail[threadIdx.x] = 0.f;
}

// ---------------- numpy-pairwise helpers ----------------
// lanes 0..31: lane = 8*k + j holds accumulator j of base-block k (128 elems,
// 8 accumulators, 16 sequential strided adds). shfl-xor tree reproduces
// ((r0+r1)+(r2+r3))+((r4+r5)+(r6+r7)) per block, then (B0+B1)+(B2+B3).
__device__ __forceinline__ float pairwise_combine(float r) {
    float o;
    o = __shfl_xor(r, 1, 64);  r = __fadd_rn(r, o);
    o = __shfl_xor(r, 2, 64);  r = __fadd_rn(r, o);
    o = __shfl_xor(r, 4, 64);  r = __fadd_rn(r, o);
    o = __shfl_xor(r, 8, 64);  r = __fadd_rn(r, o);
    o = __shfl_xor(r, 16, 64); r = __fadd_rn(r, o);
    return r;   // lane 0 holds the exact numpy pairwise sum of 512 elems
}

// ---------------- norms: np.linalg.norm (Frobenius, pairwise) in f32 ----------------
__global__ void k_norms(const float* __restrict__ w1, const float* __restrict__ w2,
                        float* __restrict__ norms) {
    __shared__ float buf[2][C_];
    int wv = threadIdx.x >> 6, lane = threadIdx.x & 63;
    const float* w = (wv == 0) ? w1 : w2;
    float4* b4 = (float4*)buf[wv];
    const float4* w4 = (const float4*)w;
    b4[lane] = w4[lane];
    b4[lane + 64] = w4[lane + 64];
    __syncthreads();
    float r = 0.f;
    if (lane < 32) {
        int base = (lane >> 3) * 128 + (lane & 7);
        float v = buf[wv][base];
        r = __fmul_rn(v, v);
        for (int i = 1; i < 16; ++i) {
            float u = buf[wv][base + 8 * i];
            r = __fadd_rn(r, __fmul_rn(u, u));
        }
    }
    r = pairwise_combine(r);
    if (lane == 0) norms[wv] = __fsqrt_rn(r);
}

// ---------------- fitness: exact np f32 pairwise dot, /norm, tanh ----------------
__global__ void k_fit(const float* __restrict__ x, const float* __restrict__ w,
                      const float* __restrict__ norms, int normIdx,
                      int rowOff, int nRows, float* __restrict__ fs,
                      float* __restrict__ fitOut) {
    __shared__ float wbuf[C_];
    __shared__ float xbuf[4][C_];
    for (int j = threadIdx.x; j < C_; j += 256) wbuf[j] = w[j];
    int wv = threadIdx.x >> 6, lane = threadIdx.x & 63;
    int gw = blockIdx.x * 4 + wv;       // grids are exact multiples of 4
    const float4* row = (const float4*)(x + (size_t)(rowOff + gw) * C_);
    float4* xb4 = (float4*)xbuf[wv];
    xb4[lane] = row[lane];
    xb4[lane + 64] = row[lane + 64];
    __syncthreads();
    float r = 0.f;
    if (lane < 32) {
        int base = (lane >> 3) * 128 + (lane & 7);
        r = __fmul_rn(xbuf[wv][base], wbuf[base]);
        for (int i = 1; i < 16; ++i) {
            int c = base + 8 * i;
            r = __fadd_rn(r, __fmul_rn(xbuf[wv][c], wbuf[c]));
        }
    }
    r = pairwise_combine(r);
    if (lane == 0) {
        float q = __fdiv_rn(r, norms[normIdx]);
        float f = (float)tanh((double)q);
        fs[gw] = f;
        fitOut[gw] = f;
    }
    (void)nRows;
}

// ---------------- rank of f1 (stable, f32 keys): tiled partial counts ----------------
#define RJ 512
__global__ void k_rank_partial(const float* __restrict__ f1s, int* __restrict__ rank) {
    __shared__ float buf[RJ];
    int i = blockIdx.x * 256 + threadIdx.x;
    int jbase = blockIdx.y * RJ;
    for (int j = threadIdx.x; j < RJ; j += 256) buf[j] = f1s[jbase + j];
    float fi = f1s[i];
    __syncthreads();
    int r = 0;
    #pragma unroll 8
    for (int j = 0; j < RJ; ++j) {
        float fj = buf[j];
        int jj = jbase + j;
        r += (int)((fj < fi) || (fj == fi && jj < i));
    }
    atomicAdd(&rank[i], r);
}

__global__ void k_thr_emit(const int* __restrict__ rank, int* __restrict__ thr1) {
    int i = blockIdx.x * blockDim.x + threadIdx.x;
    if (i >= N1_) return;
    int r = rank[i];
    if (r % 10 == 0) thr1[r / 10] = i;
}

__global__ void k_thr_gather(const int* __restrict__ thr1, const float* __restrict__ xy,
                             const float* __restrict__ f1s, float* __restrict__ thrXYF) {
    int k = blockIdx.x * blockDim.x + threadIdx.x;
    if (k >= K1_) return;
    int i = thr1[k];
    thrXYF[3 * k + 0] = xy[(size_t)(1 + i) * 2 + 0];
    thrXYF[3 * k + 1] = xy[(size_t)(1 + i) * 2 + 1];
    thrXYF[3 * k + 2] = f1s[i];
}

// exact f32 emulation of sqrt((ax-bx)^2+(ay-by)^2) + |af-bf|
__device__ __forceinline__ float pair_dist_f32(float ax, float ay, float af,
                                               float bx, float by, float bf) {
    float dx = __fsub_rn(ax, bx);
    float dy = __fsub_rn(ay, by);
    float dx2 = __fmul_rn(dx, dx);
    float dy2 = __fmul_rn(dy, dy);
    float ss = __fadd_rn(dx2, dy2);
    float dxy = __fsqrt_rn(ss);
    float df = fabsf(__fsub_rn(af, bf));
    return __fadd_rn(dxy, df);
}

// ---------------- level-1 clustering: one wave per row, lanes split K1 ----------------
__global__ void k_cluster1(const float* __restrict__ xy, const float* __restrict__ f1s,
                           const float* __restrict__ thrXYF,
                           int* __restrict__ cluster1, int* __restrict__ clusterAll,
                           float* __restrict__ outCluster) {
    __shared__ float t[K1_ * 3];
    for (int j = threadIdx.x; j < K1_ * 3; j += blockDim.x) t[j] = thrXYF[j];
    __syncthreads();
    if (blockIdx.x == 0 && threadIdx.x == 0) { clusterAll[0] = 0; outCluster[0] = 0.0f; }
    int gw = blockIdx.x * (blockDim.x >> 6) + (threadIdx.x >> 6);
    int lane = threadIdx.x & 63;
    if (gw >= N1_) return;
    float xi = xy[(size_t)(1 + gw) * 2 + 0];
    float yi = xy[(size_t)(1 + gw) * 2 + 1];
    float fi = f1s[gw];
    float best = INFINITY; int bk = 0x7fffffff;
    for (int k = lane; k < K1_; k += 64) {
        float d = pair_dist_f32(t[3 * k + 0], t[3 * k + 1], t[3 * k + 2], xi, yi, fi);
        if (d < best || (d == best && k < bk)) { best = d; bk = k; }
    }
    for (int off = 32; off > 0; off >>= 1) {
        float ob = __shfl_down(best, off, 64);
        int ok = __shfl_down(bk, off, 64);
        if (ob < best || (ob == best && ok < bk)) { best = ob; bk = ok; }
    }
    if (lane == 0) {
        cluster1[gw] = bk;
        clusterAll[1 + gw] = bk + 1;
        outCluster[1 + gw] = (float)(bk + 1);
    }
}

// ---------------- min(tree2) ----------------
__global__ void k_mintree(const int* __restrict__ tree, int* __restrict__ minTree) {
    int i = blockIdx.x * blockDim.x + threadIdx.x;
    if (i >= N2_) return;
    int v = tree[1 + N1_ + i];
    for (int off = 32; off > 0; off >>= 1) v = min(v, __shfl_down(v, off, 64));
    if ((threadIdx.x & 63) == 0) atomicMin(minTree, v);
}

// ---------------- parents + per-parent counts ----------------
__global__ void k_parents(const int* __restrict__ tree, const int* __restrict__ cluster1,
                          const int* __restrict__ minTree,
                          int* __restrict__ parents, int* __restrict__ countP) {
    int i = blockIdx.x * blockDim.x + threadIdx.x;
    if (i >= N2_) return;
    int p = cluster1[tree[1 + N1_ + i] - minTree[0]];
    parents[i] = p;
    atomicAdd(&countP[p], 1);
}

// ---------------- single-block exclusive scan (n up to ~5k) ----------------
__global__ void k_scan(const int* __restrict__ cnt, int* __restrict__ start, int n) {
    __shared__ int partial[1024];
    int t = threadIdx.x;
    int per = (n + 1023) / 1024;
    int lo = t * per;
    int hi = lo + per; if (hi > n) hi = n;
    int s = 0;
    if (lo < n) for (int i = lo; i < hi; ++i) s += cnt[i];
    partial[t] = s;
    __syncthreads();
    for (int off = 1; off < 1024; off <<= 1) {
        int v = (t >= off) ? partial[t - off] : 0;
        __syncthreads();
        partial[t] += v;
        __syncthreads();
    }
    int base = (t > 0) ? partial[t - 1] : 0;
    if (lo < n) for (int i = lo; i < hi; ++i) { start[i] = base; base += cnt[i]; }
    if (t == 1023) start[n] = partial[1023];
}

// ---------------- STABLE deterministic bucket scatter: parents ----------------
__global__ void kA_count(const int* __restrict__ parents, int* __restrict__ bc) {
    __shared__ int hist[K1_];
    for (int j = threadIdx.x; j < K1_; j += 512) hist[j] = 0;
    __syncthreads();
    int i = blockIdx.x * 512 + threadIdx.x;
    atomicAdd(&hist[parents[i]], 1);
    __syncthreads();
    for (int j = threadIdx.x; j < K1_; j += 512) bc[(size_t)j * NB2 + blockIdx.x] = hist[j];
}

__global__ void kA_scan(const int* __restrict__ startP, int* __restrict__ bc) {
    int p = blockIdx.x * 256 + threadIdx.x;
    if (p >= K1_) return;
    int run = startP[p];
    int* row = bc + (size_t)p * NB2;
    for (int b = 0; b < NB2; ++b) { int t = row[b]; row[b] = run; run += t; }
}

__global__ void kA_place(const int* __restrict__ parents, const int* __restrict__ bc,
                         int* __restrict__ plist) {
    __shared__ int par[512];
    int i = blockIdx.x * 512 + threadIdx.x;
    int p = parents[i];
    par[threadIdx.x] = p;
    __syncthreads();
    int rank = 0;
    for (int j = 0; j < (int)threadIdx.x; ++j) rank += (par[j] == p);
    plist[bc[(size_t)p * NB2 + blockIdx.x] + rank] = i;
}

// ---------------- STABLE deterministic bucket scatter: clusters ----------------
__global__ void kM_count(const int* __restrict__ clusterAll, int* __restrict__ bc) {
    __shared__ int hist[M_];
    for (int j = threadIdx.x; j < M_; j += 512) hist[j] = 0;
    __syncthreads();
    int i = blockIdx.x * 512 + threadIdx.x;
    if (i < NTOT) atomicAdd(&hist[clusterAll[i]], 1);
    __syncthreads();
    for (int j = threadIdx.x; j < M_; j += 512) bc[(size_t)j * NBM + blockIdx.x] = hist[j];
}

__global__ void kM_scan(const int* __restrict__ startM, int* __restrict__ bc) {
    int c = blockIdx.x * 256 + threadIdx.x;
    if (c >= M_) return;
    int run = startM[c];
    int* row = bc + (size_t)c * NBM;
    for (int b = 0; b < NBM; ++b) { int t = row[b]; row[b] = run; run += t; }
}

__global__ void kM_place(const int* __restrict__ clusterAll, const int* __restrict__ bc,
                         int* __restrict__ lst) {
    __shared__ int par[512];
    int i = blockIdx.x * 512 + threadIdx.x;
    int c = (i < NTOT) ? clusterAll[i] : -1;
    par[threadIdx.x] = c;
    __syncthreads();
    if (i >= NTOT) return;
    int rank = 0;
    for (int j = 0; j < (int)threadIdx.x; ++j) rank += (par[j] == c);
    lst[bc[(size_t)c * NBM + blockIdx.x] + rank] = i;
}

// ---------------- per-parent first-4 in (f32 comp_key, index) order ----------------
__global__ void k_top4(const int* __restrict__ startP, const int* __restrict__ plist,
                       const float* __restrict__ f2s, int* __restrict__ cand) {
    int p = blockIdx.x * (blockDim.x >> 6) + (threadIdx.x >> 6);
    int lane = threadIdx.x & 63;
    if (p >= K1_) return;
    int lo = startP[p], hi = startP[p + 1];
    float base = (float)(4 * p);   // exact in f32
    float bk[4] = {INFINITY, INFINITY, INFINITY, INFINITY};
    int bi[4] = {-1, -1, -1, -1};
    for (int q = lo + lane; q < hi; q += 64) {
        int idx = plist[q];
        float key = __fadd_rn(base, f2s[idx]);
        for (int j = 0; j < 4; ++j) {
            bool less = (key < bk[j]) || (key == bk[j] && (unsigned)idx < (unsigned)bi[j]);
            if (less) {
                for (int r = 3; r > j; --r) { bk[r] = bk[r - 1]; bi[r] = bi[r - 1]; }
                bk[j] = key; bi[j] = idx;
                break;
            }
        }
    }
    for (int off = 1; off < 64; off <<= 1) {
        float ok_[4]; int oi[4];
        for (int j = 0; j < 4; ++j) {
            ok_[j] = __shfl_xor(bk[j], off, 64);
            oi[j]  = __shfl_xor(bi[j], off, 64);
        }
        float nk[4]; int ni[4];
        int ia = 0, ib = 0;
        for (int j = 0; j < 4; ++j) {
            bool takeA = (bk[ia] < ok_[ib]) ||
                         (bk[ia] == ok_[ib] && (unsigned)bi[ia] <= (unsigned)oi[ib]);
            if (takeA) { nk[j] = bk[ia]; ni[j] = bi[ia]; ++ia; }
            else       { nk[j] = ok_[ib]; ni[j] = oi[ib]; ++ib; }
        }
        for (int j = 0; j < 4; ++j) { bk[j] = nk[j]; bi[j] = ni[j]; }
    }
    if (lane == 0) {
        for (int j = 0; j < 4; ++j) cand[4 * p + j] = bi[j];
    }
}

// ---------------- level-2 clustering: f32 argmin (first index) ----------------
__global__ void k_cluster2(const float* __restrict__ xy, const float* __restrict__ f2s,
                           const int* __restrict__ parents, const int* __restrict__ cand,
                           int* __restrict__ clusterAll, float* __restrict__ outCluster) {
    int i = blockIdx.x * blockDim.x + threadIdx.x;
    if (i >= N2_) return;
    int p = parents[i];
    float xi = xy[(size_t)(1 + N1_ + i) * 2 + 0];
    float yi = xy[(size_t)(1 + N1_ + i) * 2 + 1];
    float fi = f2s[i];
    float best = INFINITY; int bj = 0;
    for (int j = 0; j < 4; ++j) {
        int cidx = cand[4 * p + j];
        float d;
        if (cidx < 0) {
            d = INFINITY;
        } else {
            float ax = xy[(size_t)(1 + N1_ + cidx) * 2 + 0];
            float ay = xy[(size_t)(1 + N1_ + cidx) * 2 + 1];
            float af = f2s[cidx];
            d = pair_dist_f32(ax, ay, af, xi, yi, fi);
        }
        if (d < best) { best = d; bj = j; }
    }
    int c2 = p * 4 + bj;
    clusterAll[1 + N1_ + i] = c2 + 1 + K1_;
    outCluster[1 + N1_ + i] = (float)(c2 + 1 + K1_);
}

// ---------------- count per final cluster ----------------
__global__ void k_countM(const int* __restrict__ clusterAll, int* __restrict__ cntM) {
    int i = blockIdx.x * blockDim.x + threadIdx.x;
    if (i >= NTOT) return;
    atomicAdd(&cntM[clusterAll[i]], 1);
}

// ---------------- pooled features + pooled xy ----------------
__global__ void k_pool(const float* __restrict__ x, const float* __restrict__ xy,
                       const int* __restrict__ startM, const int* __restrict__ clusterList,
                       float* __restrict__ out) {
    int m = blockIdx.x;
    int lo = startM[m], hi = startM[m + 1];
    int t = threadIdx.x;
    double s0 = 0.0, s1 = 0.0, sx = 0.0, sy = 0.0;
    for (int q = lo; q < hi; ++q) {
        int n0 = clusterList[q];
        const float2* r0 = (const float2*)(x + (size_t)n0 * C_);
        float2 a = r0[t];
        s0 += (double)a.x; s1 += (double)a.y;
        if (t == 0) sx += (double)xy[(size_t)n0 * 2 + 0];
        if (t == 1) sy += (double)xy[(size_t)n0 * 2 + 1];
    }
    double cnt = (double)((hi - lo) > 0 ? (hi - lo) : 1);
    float2* xp = (float2*)(out + OFF_XPOOL + (size_t)m * C_);
    xp[t] = make_float2((float)(s0 / cnt), (float)(s1 / cnt));
    if (t == 0) out[OFF_NXY + 2 * (size_t)m + 0] = (float)(sx / cnt);
    if (t == 1) out[OFF_NXY + 2 * (size_t)m + 1] = (float)(sy / cnt);
}

// ---------------- adjacency ----------------
__global__ void k_edges(const int* __restrict__ ei, const int* __restrict__ clusterAll,
                        float* __restrict__ A) {
    int e = blockIdx.x * blockDim.x + threadIdx.x;
    if (e >= E_) return;
    int r = clusterAll[ei[e]];
    int c = clusterAll[ei[E_ + e]];
    atomicAdd(&A[(size_t)r * M_ + c], 1.0f);
}

__global__ void k_selfloops(const int* __restrict__ clusterAll, float* __restrict__ A) {
    int i = blockIdx.x * blockDim.x + threadIdx.x;
    if (i >= NTOT) return;
    int c = clusterAll[i];
    atomicAdd(&A[(size_t)c * M_ + c], 1.0f);
}

// ---------------- trivial outputs (+ batch zeros + fit[0]) ----------------
__global__ void k_trivial(float* __restrict__ out) {
    int i = blockIdx.x * blockDim.x + threadIdx.x;
    if (i >= M_) return;
    out[OFF_NNT + i] = (i == 0) ? 0.0f : (i <= K1_ ? 1.0f : 2.0f);
    out[OFF_NTREE + i] = (i == 0) ? -1.0f : (i <= K1_ ? 0.0f : (float)(1 + (i - 1 - K1_) / 4));
    out[OFF_BATCH + i] = 0.0f;
    if (i == 0) out[OFF_FIT] = 0.0f;
}

extern "C" void kernel_launch(void* const* d_in, const int* in_sizes, int n_in,
                              void* d_out, int out_size, void* d_ws, size_t ws_size,
                              hipStream_t stream) {
    const float* x    = (const float*)d_in[0];
    const int*   ei   = (const int*)d_in[1];
    const int*   tree = (const int*)d_in[3];
    const float* xy   = (const float*)d_in[4];
    const float* w1   = (const float*)d_in[5];
    const float* w2   = (const float*)d_in[6];
    float* out = (float*)d_out;

    char* p = (char*)d_ws;
    auto alloc = [&](size_t nbytes) -> char* {
        char* r = p;
        p += (nbytes + 255) & ~(size_t)255;
        return r;
    };
    float*  f1s        = (float*)alloc((size_t)N1_ * 4);
    float*  f2s        = (float*)alloc((size_t)N2_ * 4);
    float*  norms      = (float*)alloc(16);
    int*    thr1       = (int*)alloc((size_t)K1_ * 4);
    float*  thrXYF     = (float*)alloc((size_t)K1_ * 3 * 4);
    int*    cluster1   = (int*)alloc((size_t)N1_ * 4);
    int*    clusterAll = (int*)alloc((size_t)NTOT * 4);
    int*    parentsA   = (int*)alloc((size_t)N2_ * 4);
    int*    plist      = (int*)alloc((size_t)N2_ * 4);
    int*    clusterLst = (int*)alloc((size_t)NTOT * 4);
    int*    startP     = (int*)alloc((size_t)(K1_ + 1) * 4);
    int*    startM     = (int*)alloc((size_t)(M_ + 1) * 4);
    int*    bcP        = (int*)alloc((size_t)K1_ * NB2 * 4);
    int*    bcM        = (int*)alloc((size_t)M_ * NBM * 4);
    // zero-initialized block: countP, cntM, rankArr
    size_t zeroInts = (size_t)(K1_ + M_ + N1_);
    char*   zeroBlk    = alloc(zeroInts * 4);
    int*    countP     = (int*)zeroBlk;
    int*    cntM       = countP + K1_;
    int*    rankArr    = cntM + M_;
    int*    cand       = (int*)alloc((size_t)K1_ * 4 * 4);
    int*    minTree    = (int*)alloc(4);

    hipMemsetAsync(zeroBlk, 0, zeroInts * 4, stream);
    hipMemsetAsync(minTree, 0x7F, 4, stream);               // large positive int

    // zero A (everything else in d_out is fully overwritten by kernels below)
    {
        long nA = (long)M_ * M_;
        long n4 = nA / 4;
        int ntail = (int)(nA - n4 * 4);
        float* A = out + OFF_A;
        k_zero4<<<4096, 256, 0, stream>>>((float4*)A, n4, A + n4 * 4, ntail);
    }

    k_norms<<<1, 128, 0, stream>>>(w1, w2, norms);
    k_fit<<<N1_ / 4, 256, 0, stream>>>(x, w1, norms, 0, 1, N1_, f1s, out + OFF_FIT + 1);
    k_fit<<<N2_ / 4, 256, 0, stream>>>(x, w2, norms, 1, 1 + N1_, N2_, f2s, out + OFF_FIT + 1 + N1_);
    {
        dim3 g(N1_ / 256, N1_ / RJ);
        k_rank_partial<<<g, 256, 0, stream>>>(f1s, rankArr);
    }
    k_thr_emit<<<N1_ / 256, 256, 0, stream>>>(rankArr, thr1);
    k_thr_gather<<<(K1_ + 255) / 256, 256, 0, stream>>>(thr1, xy, f1s, thrXYF);
    k_cluster1<<<N1_ / 4, 256, 0, stream>>>(xy, f1s, thrXYF, cluster1, clusterAll,
                                            out + OFF_CLUSTER);
    k_mintree<<<N2_ / 256, 256, 0, stream>>>(tree, minTree);
    k_parents<<<N2_ / 256, 256, 0, stream>>>(tree, cluster1, minTree, parentsA, countP);
    k_scan<<<1, 1024, 0, stream>>>(countP, startP, K1_);
    kA_count<<<NB2, 512, 0, stream>>>(parentsA, bcP);
    kA_scan<<<(K1_ + 255) / 256, 256, 0, stream>>>(startP, bcP);
    kA_place<<<NB2, 512, 0, stream>>>(parentsA, bcP, plist);
    k_top4<<<(K1_ + 3) / 4, 256, 0, stream>>>(startP, plist, f2s, cand);
    k_cluster2<<<N2_ / 256, 256, 0, stream>>>(xy, f2s, parentsA, cand, clusterAll,
                                              out + OFF_CLUSTER);
    k_countM<<<(NTOT + 255) / 256, 256, 0, stream>>>(clusterAll, cntM);
    k_scan<<<1, 1024, 0, stream>>>(cntM, startM, M_);
    kM_count<<<NBM, 512, 0, stream>>>(clusterAll, bcM);
    kM_scan<<<(M_ + 255) / 256, 256, 0, stream>>>(startM, bcM);
    kM_place<<<NBM, 512, 0, stream>>>(clusterAll, bcM, clusterLst);
    k_pool<<<M_, 256, 0, stream>>>(x, xy, startM, clusterLst, out);
    k_edges<<<(E_ + 255) / 256, 256, 0, stream>>>(ei, clusterAll, out + OFF_A);
    k_selfloops<<<(NTOT + 255) / 256, 256, 0, stream>>>(clusterAll, out + OFF_A);
    k_trivial<<<(M_ + 255) / 256, 256, 0, stream>>>(out);
}

// Round 7
// 801.359 us; speedup vs baseline: 2.1419x; 1.0423x over previous
//
#include <hip/hip_runtime.h>
#include <cstdint>
#include <cstddef>
#include <math.h>

#define C_     512
#define N1_    8192
#define N2_    131072
#define NTOT   139265
#define E_     1000000
#define K1_    820
#define K2_    3280
#define M_     4101
#define NB2    256      // N2 / 512
#define NBM    273      // ceil(NTOT / 512)

// d_out offsets (float elements), in reference return order
#define OFF_XPOOL   0ull
#define OFF_A       2099712ull
#define OFF_BATCH   18917913ull
#define OFF_CLUSTER 18922014ull
#define OFF_NNT     19061279ull
#define OFF_NTREE   19065380ull
#define OFF_FIT     19069481ull
#define OFF_NXY     19208746ull
#define OUT_TOTAL   19216948ull

// Discrete decisions emulate the reference's float32 arithmetic bit-exactly:
// numpy pairwise summation for dot products / norm, __f*_rn elementwise ops
// (no fma contraction), f32 keys, stable index tiebreaks. Bucket lists use a
// STABLE deterministic scatter (bit-identical output every call).
// FROZEN NUMERICS: per-row op sequence in k_fit, q-sequential f64 adds in
// k_pool — do not reorder (rounds 3/4/5 failures).

// ---------------- zero A + trivial outputs (fused) ----------------
__global__ void k_zero4(float4* __restrict__ p, long n4, float* __restrict__ tail, int ntail,
                        float* __restrict__ out) {
    long i = (long)blockIdx.x * blockDim.x + threadIdx.x;
    long stride = (long)gridDim.x * blockDim.x;
    float4 z = make_float4(0.f, 0.f, 0.f, 0.f);
    for (long k = i; k < n4; k += stride) p[k] = z;
    if (blockIdx.x == 0 && threadIdx.x < ntail) tail[threadIdx.x] = 0.f;
    if (i < M_) {
        out[OFF_NNT + i] = (i == 0) ? 0.0f : (i <= K1_ ? 1.0f : 2.0f);
        out[OFF_NTREE + i] = (i == 0) ? -1.0f : (i <= K1_ ? 0.0f : (float)(1 + (i - 1 - K1_) / 4));
        out[OFF_BATCH + i] = 0.0f;
        if (i == 0) out[OFF_FIT] = 0.0f;
    }
}

// ---------------- numpy-pairwise combine (32 partials within a half-wave) ----------------
__device__ __forceinline__ float pairwise_combine(float r) {
    float o;
    o = __shfl_xor(r, 1, 64);  r = __fadd_rn(r, o);
    o = __shfl_xor(r, 2, 64);  r = __fadd_rn(r, o);
    o = __shfl_xor(r, 4, 64);  r = __fadd_rn(r, o);
    o = __shfl_xor(r, 8, 64);  r = __fadd_rn(r, o);
    o = __shfl_xor(r, 16, 64); r = __fadd_rn(r, o);
    return r;   // lane 0 (and lane 32) hold the pairwise sum of their half's 32 partials
}

// ---------------- fitness: exact np f32 pairwise dot, /norm(w), tanh ----------------
// 4 waves/block, TWO rows per wave (lanes 0-31 = row A, 32-63 = row B).
// Norm recomputed per wave from wbuf with the identical pairwise sequence.
__global__ void k_fit(const float* __restrict__ x, const float* __restrict__ w,
                      int rowOff, float* __restrict__ fs, float* __restrict__ fitOut) {
    __shared__ float wbuf[C_];
    __shared__ float xbuf[8][C_];
    for (int j = threadIdx.x; j < C_; j += 256) wbuf[j] = w[j];
    int wv = threadIdx.x >> 6, lane = threadIdx.x & 63;
    int rowA = blockIdx.x * 8 + wv * 2;      // grids are exact multiples of 8
    const float4* rA = (const float4*)(x + (size_t)(rowOff + rowA) * C_);
    const float4* rB = (const float4*)(x + (size_t)(rowOff + rowA + 1) * C_);
    float4* xa = (float4*)xbuf[wv * 2];
    float4* xb = (float4*)xbuf[wv * 2 + 1];
    xa[lane] = rA[lane];
    xa[lane + 64] = rA[lane + 64];
    xb[lane] = rB[lane];
    xb[lane + 64] = rB[lane + 64];
    __syncthreads();
    int hl = lane & 31;
    int base = (hl >> 3) * 128 + (hl & 7);
    const float* xr = xbuf[wv * 2 + (lane >> 5)];
    // norm partials (both halves compute the same value)
    float nv = wbuf[base];
    float nr = __fmul_rn(nv, nv);
    // dot partials
    float r = __fmul_rn(xr[base], wbuf[base]);
    #pragma unroll
    for (int i = 1; i < 16; ++i) {
        int c = base + 8 * i;
        float u = wbuf[c];
        nr = __fadd_rn(nr, __fmul_rn(u, u));
        r = __fadd_rn(r, __fmul_rn(xr[c], u));
    }
    nr = pairwise_combine(nr);
    r = pairwise_combine(r);
    if (hl == 0) {
        float nrm = __fsqrt_rn(nr);
        float q = __fdiv_rn(r, nrm);
        float f = (float)tanh((double)q);
        int gw = rowA + (lane >> 5);
        fs[gw] = f;
        fitOut[gw] = f;
    }
}

// ---------------- rank of f1 (stable, f32 keys): tiled partial counts ----------------
#define RJ 512
__global__ void k_rank_partial(const float* __restrict__ f1s, int* __restrict__ rank) {
    __shared__ float buf[RJ];
    int i = blockIdx.x * 256 + threadIdx.x;
    int jbase = blockIdx.y * RJ;
    for (int j = threadIdx.x; j < RJ; j += 256) buf[j] = f1s[jbase + j];
    float fi = f1s[i];
    __syncthreads();
    int r = 0;
    #pragma unroll 8
    for (int j = 0; j < RJ; ++j) {
        float fj = buf[j];
        int jj = jbase + j;
        r += (int)((fj < fi) || (fj == fi && jj < i));
    }
    atomicAdd(&rank[i], r);
}

// ---------------- emit decile thresholds directly as (x,y,f) ----------------
__global__ void k_thr(const int* __restrict__ rank, const float* __restrict__ xy,
                      const float* __restrict__ f1s, float* __restrict__ thrXYF) {
    int i = blockIdx.x * blockDim.x + threadIdx.x;
    if (i >= N1_) return;
    int r = rank[i];
    if (r % 10 == 0) {
        int k = r / 10;
        thrXYF[3 * k + 0] = xy[(size_t)(1 + i) * 2 + 0];
        thrXYF[3 * k + 1] = xy[(size_t)(1 + i) * 2 + 1];
        thrXYF[3 * k + 2] = f1s[i];
    }
}

// exact f32 emulation of sqrt((ax-bx)^2+(ay-by)^2) + |af-bf|
__device__ __forceinline__ float pair_dist_f32(float ax, float ay, float af,
                                               float bx, float by, float bf) {
    float dx = __fsub_rn(ax, bx);
    float dy = __fsub_rn(ay, by);
    float dx2 = __fmul_rn(dx, dx);
    float dy2 = __fmul_rn(dy, dy);
    float ss = __fadd_rn(dx2, dy2);
    float dxy = __fsqrt_rn(ss);
    float df = fabsf(__fsub_rn(af, bf));
    return __fadd_rn(dxy, df);
}

// ---------------- level-1 clustering (+ cntM count, + node 0 init) ----------------
__global__ void k_cluster1(const float* __restrict__ xy, const float* __restrict__ f1s,
                           const float* __restrict__ thrXYF,
                           int* __restrict__ cluster1, int* __restrict__ clusterAll,
                           float* __restrict__ outCluster, int* __restrict__ cntM) {
    __shared__ float t[K1_ * 3];
    for (int j = threadIdx.x; j < K1_ * 3; j += blockDim.x) t[j] = thrXYF[j];
    __syncthreads();
    if (blockIdx.x == 0 && threadIdx.x == 0) {
        clusterAll[0] = 0; outCluster[0] = 0.0f;
        atomicAdd(&cntM[0], 1);     // node 0 -> cluster 0
    }
    int gw = blockIdx.x * (blockDim.x >> 6) + (threadIdx.x >> 6);
    int lane = threadIdx.x & 63;
    if (gw >= N1_) return;
    float xi = xy[(size_t)(1 + gw) * 2 + 0];
    float yi = xy[(size_t)(1 + gw) * 2 + 1];
    float fi = f1s[gw];
    float best = INFINITY; int bk = 0x7fffffff;
    for (int k = lane; k < K1_; k += 64) {
        float d = pair_dist_f32(t[3 * k + 0], t[3 * k + 1], t[3 * k + 2], xi, yi, fi);
        if (d < best || (d == best && k < bk)) { best = d; bk = k; }
    }
    for (int off = 32; off > 0; off >>= 1) {
        float ob = __shfl_down(best, off, 64);
        int ok = __shfl_down(bk, off, 64);
        if (ob < best || (ob == best && ok < bk)) { best = ob; bk = ok; }
    }
    if (lane == 0) {
        cluster1[gw] = bk;
        clusterAll[1 + gw] = bk + 1;
        outCluster[1 + gw] = (float)(bk + 1);
        atomicAdd(&cntM[bk + 1], 1);
    }
}

// ---------------- min(tree2) ----------------
__global__ void k_mintree(const int* __restrict__ tree, int* __restrict__ minTree) {
    int i = blockIdx.x * blockDim.x + threadIdx.x;
    if (i >= N2_) return;
    int v = tree[1 + N1_ + i];
    for (int off = 32; off > 0; off >>= 1) v = min(v, __shfl_down(v, off, 64));
    if ((threadIdx.x & 63) == 0) atomicMin(minTree, v);
}

// ---------------- parents + per-parent counts ----------------
__global__ void k_parents(const int* __restrict__ tree, const int* __restrict__ cluster1,
                          const int* __restrict__ minTree,
                          int* __restrict__ parents, int* __restrict__ countP) {
    int i = blockIdx.x * blockDim.x + threadIdx.x;
    if (i >= N2_) return;
    int p = cluster1[tree[1 + N1_ + i] - minTree[0]];
    parents[i] = p;
    atomicAdd(&countP[p], 1);
}

// ---------------- single-block exclusive scan (n up to ~5k) ----------------
__global__ void k_scan(const int* __restrict__ cnt, int* __restrict__ start, int n) {
    __shared__ int partial[1024];
    int t = threadIdx.x;
    int per = (n + 1023) / 1024;
    int lo = t * per;
    int hi = lo + per; if (hi > n) hi = n;
    int s = 0;
    if (lo < n) for (int i = lo; i < hi; ++i) s += cnt[i];
    partial[t] = s;
    __syncthreads();
    for (int off = 1; off < 1024; off <<= 1) {
        int v = (t >= off) ? partial[t - off] : 0;
        __syncthreads();
        partial[t] += v;
        __syncthreads();
    }
    int base = (t > 0) ? partial[t - 1] : 0;
    if (lo < n) for (int i = lo; i < hi; ++i) { start[i] = base; base += cnt[i]; }
    if (t == 1023) start[n] = partial[1023];
}

// ---------------- STABLE deterministic bucket scatter: parents ----------------
__global__ void kA_count(const int* __restrict__ parents, int* __restrict__ bc) {
    __shared__ int hist[K1_];
    for (int j = threadIdx.x; j < K1_; j += 512) hist[j] = 0;
    __syncthreads();
    int i = blockIdx.x * 512 + threadIdx.x;
    atomicAdd(&hist[parents[i]], 1);
    __syncthreads();
    for (int j = threadIdx.x; j < K1_; j += 512) bc[(size_t)j * NB2 + blockIdx.x] = hist[j];
}

__global__ void kA_scan(const int* __restrict__ startP, int* __restrict__ bc) {
    int p = blockIdx.x * 256 + threadIdx.x;
    if (p >= K1_) return;
    int run = startP[p];
    int* row = bc + (size_t)p * NB2;
    for (int b = 0; b < NB2; ++b) { int t = row[b]; row[b] = run; run += t; }
}

__global__ void kA_place(const int* __restrict__ parents, const int* __restrict__ bc,
                         int* __restrict__ plist) {
    __shared__ int par[512];
    int i = blockIdx.x * 512 + threadIdx.x;
    int p = parents[i];
    par[threadIdx.x] = p;
    __syncthreads();
    int rank = 0;
    for (int j = 0; j < (int)threadIdx.x; ++j) rank += (par[j] == p);
    plist[bc[(size_t)p * NB2 + blockIdx.x] + rank] = i;
}

// ---------------- STABLE deterministic bucket scatter: clusters ----------------
__global__ void kM_count(const int* __restrict__ clusterAll, int* __restrict__ bc) {
    __shared__ int hist[M_];
    for (int j = threadIdx.x; j < M_; j += 512) hist[j] = 0;
    __syncthreads();
    int i = blockIdx.x * 512 + threadIdx.x;
    if (i < NTOT) atomicAdd(&hist[clusterAll[i]], 1);
    __syncthreads();
    for (int j = threadIdx.x; j < M_; j += 512) bc[(size_t)j * NBM + blockIdx.x] = hist[j];
}

__global__ void kM_scan(const int* __restrict__ startM, int* __restrict__ bc) {
    int c = blockIdx.x * 256 + threadIdx.x;
    if (c >= M_) return;
    int run = startM[c];
    int* row = bc + (size_t)c * NBM;
    for (int b = 0; b < NBM; ++b) { int t = row[b]; row[b] = run; run += t; }
}

__global__ void kM_place(const int* __restrict__ clusterAll, const int* __restrict__ bc,
                         int* __restrict__ lst) {
    __shared__ int par[512];
    int i = blockIdx.x * 512 + threadIdx.x;
    int c = (i < NTOT) ? clusterAll[i] : -1;
    par[threadIdx.x] = c;
    __syncthreads();
    if (i >= NTOT) return;
    int rank = 0;
    for (int j = 0; j < (int)threadIdx.x; ++j) rank += (par[j] == c);
    lst[bc[(size_t)c * NBM + blockIdx.x] + rank] = i;
}

// ---------------- per-parent first-4 in (f32 comp_key, index) order ----------------
__global__ void k_top4(const int* __restrict__ startP, const int* __restrict__ plist,
                       const float* __restrict__ f2s, int* __restrict__ cand) {
    int p = blockIdx.x * (blockDim.x >> 6) + (threadIdx.x >> 6);
    int lane = threadIdx.x & 63;
    if (p >= K1_) return;
    int lo = startP[p], hi = startP[p + 1];
    float base = (float)(4 * p);   // exact in f32
    float bk[4] = {INFINITY, INFINITY, INFINITY, INFINITY};
    int bi[4] = {-1, -1, -1, -1};
    for (int q = lo + lane; q < hi; q += 64) {
        int idx = plist[q];
        float key = __fadd_rn(base, f2s[idx]);
        for (int j = 0; j < 4; ++j) {
            bool less = (key < bk[j]) || (key == bk[j] && (unsigned)idx < (unsigned)bi[j]);
            if (less) {
                for (int r = 3; r > j; --r) { bk[r] = bk[r - 1]; bi[r] = bi[r - 1]; }
                bk[j] = key; bi[j] = idx;
                break;
            }
        }
    }
    for (int off = 1; off < 64; off <<= 1) {
        float ok_[4]; int oi[4];
        for (int j = 0; j < 4; ++j) {
            ok_[j] = __shfl_xor(bk[j], off, 64);
            oi[j]  = __shfl_xor(bi[j], off, 64);
        }
        float nk[4]; int ni[4];
        int ia = 0, ib = 0;
        for (int j = 0; j < 4; ++j) {
            bool takeA = (bk[ia] < ok_[ib]) ||
                         (bk[ia] == ok_[ib] && (unsigned)bi[ia] <= (unsigned)oi[ib]);
            if (takeA) { nk[j] = bk[ia]; ni[j] = bi[ia]; ++ia; }
            else       { nk[j] = ok_[ib]; ni[j] = oi[ib]; ++ib; }
        }
        for (int j = 0; j < 4; ++j) { bk[j] = nk[j]; bi[j] = ni[j]; }
    }
    if (lane == 0) {
        for (int j = 0; j < 4; ++j) cand[4 * p + j] = bi[j];
    }
}

// ---------------- level-2 clustering: f32 argmin (first index) + cntM ----------------
__global__ void k_cluster2(const float* __restrict__ xy, const float* __restrict__ f2s,
                           const int* __restrict__ parents, const int* __restrict__ cand,
                           int* __restrict__ clusterAll, float* __restrict__ outCluster,
                           int* __restrict__ cntM) {
    int i = blockIdx.x * blockDim.x + threadIdx.x;
    if (i >= N2_) return;
    int p = parents[i];
    float xi = xy[(size_t)(1 + N1_ + i) * 2 + 0];
    float yi = xy[(size_t)(1 + N1_ + i) * 2 + 1];
    float fi = f2s[i];
    float best = INFINITY; int bj = 0;
    for (int j = 0; j < 4; ++j) {
        int cidx = cand[4 * p + j];
        float d;
        if (cidx < 0) {
            d = INFINITY;
        } else {
            float ax = xy[(size_t)(1 + N1_ + cidx) * 2 + 0];
            float ay = xy[(size_t)(1 + N1_ + cidx) * 2 + 1];
            float af = f2s[cidx];
            d = pair_dist_f32(ax, ay, af, xi, yi, fi);
        }
        if (d < best) { best = d; bj = j; }
    }
    int c2 = p * 4 + bj;
    int c = c2 + 1 + K1_;
    clusterAll[1 + N1_ + i] = c;
    outCluster[1 + N1_ + i] = (float)c;
    atomicAdd(&cntM[c], 1);
}

// ---------------- pooled features + pooled xy: 128 thr x float4, 2-row unroll ----------------
__global__ void k_pool(const float* __restrict__ x, const float* __restrict__ xy,
                       const int* __restrict__ startM, const int* __restrict__ clusterList,
                       float* __restrict__ out) {
    int m = blockIdx.x;
    int lo = startM[m], hi = startM[m + 1];
    int t = threadIdx.x;   // 0..127, channels 4t..4t+3
    double s0 = 0.0, s1 = 0.0, s2 = 0.0, s3 = 0.0, sx = 0.0, sy = 0.0;
    int q = lo;
    for (; q + 1 < hi; q += 2) {
        int n0 = clusterList[q];
        int n1 = clusterList[q + 1];
        float4 a = ((const float4*)(x + (size_t)n0 * C_))[t];
        float4 b = ((const float4*)(x + (size_t)n1 * C_))[t];
        s0 += (double)a.x; s1 += (double)a.y; s2 += (double)a.z; s3 += (double)a.w;
        s0 += (double)b.x; s1 += (double)b.y; s2 += (double)b.z; s3 += (double)b.w;
        if (t == 0) sx += (double)xy[(size_t)n0 * 2 + 0] + (double)xy[(size_t)n1 * 2 + 0];
        if (t == 1) sy += (double)xy[(size_t)n0 * 2 + 1] + (double)xy[(size_t)n1 * 2 + 1];
    }
    if (q < hi) {
        int n0 = clusterList[q];
        float4 a = ((const float4*)(x + (size_t)n0 * C_))[t];
        s0 += (double)a.x; s1 += (double)a.y; s2 += (double)a.z; s3 += (double)a.w;
        if (t == 0) sx += (double)xy[(size_t)n0 * 2 + 0];
        if (t == 1) sy += (double)xy[(size_t)n0 * 2 + 1];
    }
    double cnt = (double)((hi - lo) > 0 ? (hi - lo) : 1);
    float4* xp = (float4*)(out + OFF_XPOOL + (size_t)m * C_);
    xp[t] = make_float4((float)(s0 / cnt), (float)(s1 / cnt),
                        (float)(s2 / cnt), (float)(s3 / cnt));
    if (t == 0) out[OFF_NXY + 2 * (size_t)m + 0] = (float)(sx / cnt);
    if (t == 1) out[OFF_NXY + 2 * (size_t)m + 1] = (float)(sy / cnt);
}

// ---------------- adjacency: edges + self-loops fused ----------------
__global__ void k_edges(const int* __restrict__ ei, const int* __restrict__ clusterAll,
                        float* __restrict__ A) {
    int i = blockIdx.x * blockDim.x + threadIdx.x;
    if (i < E_) {
        int r = clusterAll[ei[i]];
        int c = clusterAll[ei[E_ + i]];
        atomicAdd(&A[(size_t)r * M_ + c], 1.0f);
    } else {
        int n = i - E_;
        if (n < NTOT) {
            int c = clusterAll[n];
            atomicAdd(&A[(size_t)c * M_ + c], 1.0f);
        }
    }
}

extern "C" void kernel_launch(void* const* d_in, const int* in_sizes, int n_in,
                              void* d_out, int out_size, void* d_ws, size_t ws_size,
                              hipStream_t stream) {
    const float* x    = (const float*)d_in[0];
    const int*   ei   = (const int*)d_in[1];
    const int*   tree = (const int*)d_in[3];
    const float* xy   = (const float*)d_in[4];
    const float* w1   = (const float*)d_in[5];
    const float* w2   = (const float*)d_in[6];
    float* out = (float*)d_out;

    char* p = (char*)d_ws;
    auto alloc = [&](size_t nbytes) -> char* {
        char* r = p;
        p += (nbytes + 255) & ~(size_t)255;
        return r;
    };
    float*  f1s        = (float*)alloc((size_t)N1_ * 4);
    float*  f2s        = (float*)alloc((size_t)N2_ * 4);
    float*  thrXYF     = (float*)alloc((size_t)K1_ * 3 * 4);
    int*    cluster1   = (int*)alloc((size_t)N1_ * 4);
    int*    clusterAll = (int*)alloc((size_t)NTOT * 4);
    int*    parentsA   = (int*)alloc((size_t)N2_ * 4);
    int*    plist      = (int*)alloc((size_t)N2_ * 4);
    int*    clusterLst = (int*)alloc((size_t)NTOT * 4);
    int*    startP     = (int*)alloc((size_t)(K1_ + 1) * 4);
    int*    startM     = (int*)alloc((size_t)(M_ + 1) * 4);
    int*    bcP        = (int*)alloc((size_t)K1_ * NB2 * 4);
    int*    bcM        = (int*)alloc((size_t)M_ * NBM * 4);
    // zero-initialized block: countP, cntM, rankArr
    size_t zeroInts = (size_t)(K1_ + M_ + N1_);
    char*   zeroBlk    = alloc(zeroInts * 4);
    int*    countP     = (int*)zeroBlk;
    int*    cntM       = countP + K1_;
    int*    rankArr    = cntM + M_;
    int*    cand       = (int*)alloc((size_t)K1_ * 4 * 4);
    int*    minTree    = (int*)alloc(4);

    hipMemsetAsync(zeroBlk, 0, zeroInts * 4, stream);
    hipMemsetAsync(minTree, 0x7F, 4, stream);               // large positive int

    // zero A + trivial outputs
    {
        long nA = (long)M_ * M_;
        long n4 = nA / 4;
        int ntail = (int)(nA - n4 * 4);
        float* A = out + OFF_A;
        k_zero4<<<4096, 256, 0, stream>>>((float4*)A, n4, A + n4 * 4, ntail, out);
    }

    k_fit<<<N1_ / 8, 256, 0, stream>>>(x, w1, 1, f1s, out + OFF_FIT + 1);
    k_fit<<<N2_ / 8, 256, 0, stream>>>(x, w2, 1 + N1_, f2s, out + OFF_FIT + 1 + N1_);
    {
        dim3 g(N1_ / 256, N1_ / RJ);
        k_rank_partial<<<g, 256, 0, stream>>>(f1s, rankArr);
    }
    k_thr<<<N1_ / 256, 256, 0, stream>>>(rankArr, xy, f1s, thrXYF);
    k_cluster1<<<N1_ / 4, 256, 0, stream>>>(xy, f1s, thrXYF, cluster1, clusterAll,
                                            out + OFF_CLUSTER, cntM);
    k_mintree<<<N2_ / 256, 256, 0, stream>>>(tree, minTree);
    k_parents<<<N2_ / 256, 256, 0, stream>>>(tree, cluster1, minTree, parentsA, countP);
    k_scan<<<1, 1024, 0, stream>>>(countP, startP, K1_);
    kA_count<<<NB2, 512, 0, stream>>>(parentsA, bcP);
    kA_scan<<<(K1_ + 255) / 256, 256, 0, stream>>>(startP, bcP);
    kA_place<<<NB2, 512, 0, stream>>>(parentsA, bcP, plist);
    k_top4<<<(K1_ + 3) / 4, 256, 0, stream>>>(startP, plist, f2s, cand);
    k_cluster2<<<N2_ / 256, 256, 0, stream>>>(xy, f2s, parentsA, cand, clusterAll,
                                              out + OFF_CLUSTER, cntM);
    k_scan<<<1, 1024, 0, stream>>>(cntM, startM, M_);
    kM_count<<<NBM, 512, 0, stream>>>(clusterAll, bcM);
    kM_scan<<<(M_ + 255) / 256, 256, 0, stream>>>(startM, bcM);
    kM_place<<<NBM, 512, 0, stream>>>(clusterAll, bcM, clusterLst);
    k_pool<<<M_, 128, 0, stream>>>(x, xy, startM, clusterLst, out);
    k_edges<<<(E_ + NTOT + 255) / 256, 256, 0, stream>>>(ei, clusterAll, out + OFF_A);
}